// Round 2
// baseline (725.943 us; speedup 1.0000x reference)
//
#include <hip/hip_runtime.h>

#define NN 100000
#define NE 1600000
#define DD 128
#define CAP 56      // padded-CSR capacity; P(Poisson(16) >= 56) ~ 5e-15
#define NGROUP 256  // edge-slice groups for filtered scatter

// ---------- bf16 helpers (manual, RNE) ----------
static __device__ __forceinline__ unsigned short f2b(float f) {
  unsigned int x = __float_as_uint(f);
  unsigned int r = x + 0x7fffu + ((x >> 16) & 1u);
  return (unsigned short)(r >> 16);
}
static __device__ __forceinline__ float b2f(unsigned short u) {
  return __uint_as_float(((unsigned int)u) << 16);
}

typedef __attribute__((ext_vector_type(8))) short short8;
typedef __attribute__((ext_vector_type(4))) float f32x4;

union V8 {
  uint4 u4;
  short8 s8;
  unsigned short us[8];
};

// Sliced feature layout: xs[slice][node][16], slice = col >> 4, elem = col & 15.
// A 16-col slice is 100000*32B = 3.2 MB -> fits one XCD's 4 MB L2.

// ---------- edge-index dtype detector ----------
__global__ void detect_k(const int* __restrict__ ei, int* __restrict__ flag) {
  int v = ei[2 * threadIdx.x + 1];
  unsigned long long b = __ballot(v != 0);
  if (threadIdx.x == 0) *flag = (b == 0ull) ? 1 : 0;
}

// ---------- fp32 -> bf16 cast into sliced layout ----------
__global__ __launch_bounds__(256) void cast_k(const float* __restrict__ x,
                                              unsigned short* __restrict__ x16s) {
  int j = blockIdx.x * 256 + threadIdx.x;  // 1.6M items, item = 8 cols of one node
  int slice = j / (NN * 2);
  int r = j - slice * (NN * 2);
  int node = r >> 1;
  int half = r & 1;
  const float* src = x + (size_t)node * DD + slice * 16 + half * 8;
  f32x4 a = *(const f32x4*)src;
  f32x4 b = *(const f32x4*)(src + 4);
  V8 v;
#pragma unroll
  for (int k = 0; k < 4; ++k) {
    v.us[k] = f2b(a[k]);
    v.us[4 + k] = f2b(b[k]);
  }
  *(uint4*)(x16s + ((size_t)slice * NN + node) * 16 + half * 8) = v.u4;
}

// ---------- pack edges to int2 (src,dst) + zero cnt + zero all BN stat buffers ----------
__global__ __launch_bounds__(256) void pack_k(const int* __restrict__ ei,
                                              int2* __restrict__ packed,
                                              int* __restrict__ cnt,
                                              float* __restrict__ stats,
                                              const int* __restrict__ flag) {
  const int mode = *flag;
  const int gid = blockIdx.x * 256 + threadIdx.x;
  int s, d;
  if (mode) {  // int64 little-endian, values < 2^31: low word at even offset
    s = ((const int2*)ei)[gid].x;
    d = ((const int2*)ei)[(size_t)NE + gid].x;
  } else {
    s = ei[gid];
    d = ei[NE + gid];
  }
  packed[gid] = make_int2(s, d);
  if (gid < NN) cnt[gid] = 0;
  if (gid < 1024) stats[gid] = 0.f;  // 4 layers x (sum[128], sumsq[128])
}

// ---------- padded-CSR scatter, XCD-range-filtered; TRANSPOSED target ----------
// csrT[c][node]: entry c of node's list at csrT + c*NN + node, so the gather's
// index reads are coalesced (c is wave-uniform, node is lane-consecutive).
__global__ __launch_bounds__(256) void scatter_k(const int2* __restrict__ packed,
                                                 int* __restrict__ cnt,
                                                 int* __restrict__ csrT) {
  const int r = blockIdx.x & 7;
  const int g = blockIdx.x >> 3;
  const int lo = r * (NN / 8), hi = lo + (NN / 8);
  for (int e = g * 256 + threadIdx.x; e < NE; e += NGROUP * 256) {
    int2 sd = packed[e];
    if (sd.y >= lo && sd.y < hi) {
      int c = atomicAdd(&cnt[sd.y], 1);
      if (c < CAP) csrT[(size_t)c * NN + sd.y] = sd.x;
    }
  }
}

// ---------- weight prep: transpose+cast all 7 matrices to bf16 wT[n][k] ----------
__global__ __launch_bounds__(256) void wprep_k(const float* __restrict__ W1,
                                               const float* __restrict__ W2,
                                               const float* __restrict__ fW1,
                                               const float* __restrict__ fW2,
                                               unsigned short* __restrict__ wt) {
  int b = blockIdx.x;
  const float* src;
  int moff, N;
  if (b < 192) {
    int m = b >> 6;
    src = W1 + m * 16384;
    moff = m * 16384;
    N = 128;
    b &= 63;
  } else if (b < 384) {
    int m = (b - 192) >> 6;
    src = W2 + m * 16384;
    moff = (3 + m) * 16384;
    N = 128;
    b = (b - 192) & 63;
  } else if (b < 448) {
    src = fW1;
    moff = 6 * 16384;
    N = 128;
    b -= 384;
  } else {
    src = fW2;
    moff = 7 * 16384;
    N = 64;
    b -= 448;
  }
  int idx = b * 256 + threadIdx.x;  // n*128 + k
  int n = idx >> 7, k = idx & 127;
  if (n < N) wt[moff + idx] = f2b(src[(size_t)k * N + n]);
}

// ---------- slice-partitioned gather: h16s[s][node] = x16s[s][node] + sum x16s[s][src] ----------
// slice = blockIdx & 7 -> all blocks of slice s land on XCD s (round-robin),
// so the 3.2 MB slice of x16s stays resident in that XCD's L2.
// No LDS, ~48 VGPR -> full occupancy; c is uniform across active lanes.
__global__ __launch_bounds__(256) void gather_k(const int* __restrict__ cnt,
                                                const int* __restrict__ csrT,
                                                const unsigned short* __restrict__ x16s,
                                                unsigned short* __restrict__ h16s) {
  const int s = blockIdx.x & 7;
  const int node = (blockIdx.x >> 3) * 256 + threadIdx.x;
  if (node >= NN) return;
  const unsigned short* xs = x16s + (size_t)s * NN * 16;
  float ac[16];
  {
    V8 v0, v1;
    v0.u4 = *(const uint4*)(xs + (size_t)node * 16);
    v1.u4 = *(const uint4*)(xs + (size_t)node * 16 + 8);
#pragma unroll
    for (int j = 0; j < 8; ++j) {
      ac[j] = b2f(v0.us[j]);
      ac[8 + j] = b2f(v1.us[j]);
    }
  }
  const int cn = cnt[node];
  int c = 0;
  for (; c + 2 <= cn; c += 2) {
    const int s0 = csrT[(size_t)c * NN + node];
    const int s1 = csrT[(size_t)(c + 1) * NN + node];
    V8 a0, a1, b0, b1;
    a0.u4 = *(const uint4*)(xs + (size_t)s0 * 16);
    a1.u4 = *(const uint4*)(xs + (size_t)s0 * 16 + 8);
    b0.u4 = *(const uint4*)(xs + (size_t)s1 * 16);
    b1.u4 = *(const uint4*)(xs + (size_t)s1 * 16 + 8);
#pragma unroll
    for (int j = 0; j < 8; ++j) {
      ac[j] += b2f(a0.us[j]) + b2f(b0.us[j]);
      ac[8 + j] += b2f(a1.us[j]) + b2f(b1.us[j]);
    }
  }
  if (c < cn) {
    const int s0 = csrT[(size_t)c * NN + node];
    V8 a0, a1;
    a0.u4 = *(const uint4*)(xs + (size_t)s0 * 16);
    a1.u4 = *(const uint4*)(xs + (size_t)s0 * 16 + 8);
#pragma unroll
    for (int j = 0; j < 8; ++j) {
      ac[j] += b2f(a0.us[j]);
      ac[8 + j] += b2f(a1.us[j]);
    }
  }
  V8 o0, o1;
#pragma unroll
  for (int j = 0; j < 8; ++j) {
    o0.us[j] = f2b(ac[j]);
    o1.us[j] = f2b(ac[8 + j]);
  }
  unsigned short* hs = h16s + (size_t)s * NN * 16 + (size_t)node * 16;
  *(uint4*)hs = o0.u4;
  *(uint4*)(hs + 8) = o1.u4;
}

// ---------- MFMA GEMM: C[M x NCOLS] = A[M x 128] @ wT^T + bias ----------
// wT is pre-transposed bf16 [NCOLS][128].
// AMODE: 1 = A bf16 plain, 2 = A bf16 with BN(scale,shift from raw stats)+ReLU
// EPI:   0 = store bf16, 1 = relu + store bf16, 2 = store fp32
// STATS: 1 = accumulate per-column sum/sumsq of the (rounded) output
// ASLICED: A is in sliced layout [8][NN][16] (slice = 2*kc + (quad>>1))
// CSLICED: C store in sliced layout (slice = nt, elem = l16)
template <int AMODE, int NCOLS, int EPI, int STATS, int ASLICED, int CSLICED>
__global__ __launch_bounds__(256) void gemm_k(const unsigned short* __restrict__ Aptr,
                                              const unsigned short* __restrict__ wT,
                                              const float* __restrict__ bias,
                                              const float* __restrict__ bn_stats,
                                              const float* __restrict__ gamma,
                                              const float* __restrict__ beta,
                                              void* __restrict__ Cptr,
                                              float* __restrict__ stats_out) {
  __shared__ unsigned short bT[NCOLS][136];  // 136: 16B-aligned rows, benign 2-way alias
  __shared__ float biasS[NCOLS];
  __shared__ float scS[128];
  __shared__ float shS[128];
  __shared__ float sS[NCOLS];
  __shared__ float s2S[NCOLS];
  const int tid = threadIdx.x;

  // prologue: straight vectorized copy of pre-transposed weights
  for (int i = tid; i < NCOLS * 16; i += 256) {
    int n = i >> 4, k8 = (i & 15) << 3;
    *(uint4*)&bT[n][k8] = *(const uint4*)(wT + n * 128 + k8);
  }
  if (tid < NCOLS) biasS[tid] = bias[tid];
  if (AMODE == 2 && tid < 128) {
    const float inv_n = 1.0f / (float)NN;
    float mu = bn_stats[tid] * inv_n;
    float var = bn_stats[128 + tid] * inv_n - mu * mu;
    float sc = gamma[tid] * rsqrtf(var + 1e-5f);
    scS[tid] = sc;
    shS[tid] = beta[tid] - mu * sc;
  }
  if (STATS && tid < NCOLS) {
    sS[tid] = 0.f;
    s2S[tid] = 0.f;
  }
  __syncthreads();

  const int wv = tid >> 6;
  const int lane = tid & 63;
  const int l16 = lane & 15;
  const int quad = lane >> 4;
  const int arow = blockIdx.x * 64 + wv * 16 + l16;  // A row (m = lane&15)
  const bool rv = arow < NN;

  f32x4 acc[NCOLS / 16];
#pragma unroll
  for (int nt = 0; nt < NCOLS / 16; ++nt) acc[nt] = (f32x4)(0.0f);

#pragma unroll
  for (int kc = 0; kc < 4; ++kc) {
    const int k0 = kc * 32 + quad * 8;
    V8 af;
    if (rv) {
      if (ASLICED) {
        const int slice = kc * 2 + (quad >> 1);
        af.u4 = *(const uint4*)(Aptr + ((size_t)slice * NN + arow) * 16 + (quad & 1) * 8);
      } else {
        af.u4 = *(const uint4*)(Aptr + (size_t)arow * DD + k0);
      }
    } else {
      af.u4 = make_uint4(0u, 0u, 0u, 0u);
    }
    if (AMODE == 2) {
#pragma unroll
      for (int j = 0; j < 8; ++j) {
        float f = fmaf(b2f(af.us[j]), scS[k0 + j], shS[k0 + j]);
        af.us[j] = f2b(fmaxf(f, 0.0f));
      }
    }
#pragma unroll
    for (int nt = 0; nt < NCOLS / 16; ++nt) {
      V8 bf;
      bf.u4 = *(const uint4*)&bT[nt * 16 + l16][k0];
      acc[nt] = __builtin_amdgcn_mfma_f32_16x16x32_bf16(af.s8, bf.s8, acc[nt], 0, 0, 0);
    }
  }

  // C/D layout: col = lane&15, row = quad*4 + reg
  const int r0 = blockIdx.x * 64 + wv * 16 + quad * 4;
#pragma unroll
  for (int nt = 0; nt < NCOLS / 16; ++nt) {
    const int col = nt * 16 + l16;
    const float bv = biasS[col];
    float s = 0.f, s2 = 0.f;
#pragma unroll
    for (int i = 0; i < 4; ++i) {
      const int r = r0 + i;
      if (r < NN) {
        float v = acc[nt][i] + bv;
        if (EPI == 1) v = fmaxf(v, 0.0f);
        if (EPI == 2) {
          ((float*)Cptr)[(size_t)r * NCOLS + col] = v;
        } else {
          unsigned short us = f2b(v);
          if (CSLICED) {
            ((unsigned short*)Cptr)[((size_t)nt * NN + r) * 16 + l16] = us;
          } else {
            ((unsigned short*)Cptr)[(size_t)r * NCOLS + col] = us;
          }
          if (STATS) {
            float vr = b2f(us);  // stats on rounded value (matches gemm2's input)
            s += vr;
            s2 += vr * vr;
          }
        }
      }
    }
    if (STATS) {
      s += __shfl_xor(s, 16);
      s += __shfl_xor(s, 32);
      s2 += __shfl_xor(s2, 16);
      s2 += __shfl_xor(s2, 32);
      if (quad == 0) {
        atomicAdd(&sS[col], s);
        atomicAdd(&s2S[col], s2);
      }
    }
  }
  if (STATS) {
    __syncthreads();
    if (tid < NCOLS) {
      atomicAdd(&stats_out[tid], sS[tid]);
      atomicAdd(&stats_out[128 + tid], s2S[tid]);
    }
  }
}

// ---------- launch ----------
extern "C" void kernel_launch(void* const* d_in, const int* in_sizes, int n_in,
                              void* d_out, int out_size, void* d_ws, size_t ws_size,
                              hipStream_t stream) {
  const float* x = (const float*)d_in[0];
  const int* ei = (const int*)d_in[1];
  const float* W1 = (const float*)d_in[2];
  const float* b1 = (const float*)d_in[3];
  const float* g1 = (const float*)d_in[4];
  const float* be1 = (const float*)d_in[5];
  const float* W2 = (const float*)d_in[6];
  const float* b2 = (const float*)d_in[7];
  const float* fW1 = (const float*)d_in[8];
  const float* fb1 = (const float*)d_in[9];
  const float* fg1 = (const float*)d_in[10];
  const float* fbe1 = (const float*)d_in[11];
  const float* fW2 = (const float*)d_in[12];
  const float* fb2 = (const float*)d_in[13];

  char* ws = (char*)d_ws;
  unsigned short* x16s = (unsigned short*)ws;                      // 25.6 MB sliced
  unsigned short* h16s = (unsigned short*)(ws + (size_t)25600000); // 25.6 MB sliced
  unsigned short* t16 = (unsigned short*)(ws + (size_t)51200000);  // 25.6 MB row-major
  int2* packed = (int2*)t16;  // 12.8 MB, consumed by scatter before t16 is written
  int* csrT = (int*)(ws + (size_t)76800000);      // NN*CAP*4 = 22.4 MB (transposed)
  int* cnt = (int*)(ws + (size_t)99200000);       // 400 KB
  float* stats = (float*)(ws + (size_t)99600000); // 4 KB: 4 layers x 256
  int* flag = (int*)(ws + (size_t)99604096);
  unsigned short* wt = (unsigned short*)(ws + (size_t)99605504);   // 262 KB

  const int castBlocks = (NN * 16) / 256;       // 6250
  const int gemmBlocks = (NN + 63) / 64;        // 1563
  const int edgeBlocks = NE / 256;              // 6250
  const int filtBlocks = NGROUP * 8;            // 2048
  const int gathBlocks = ((NN + 255) / 256) * 8;  // 3128

  detect_k<<<1, 64, 0, stream>>>(ei, flag);
  cast_k<<<castBlocks, 256, 0, stream>>>(x, x16s);
  pack_k<<<edgeBlocks, 256, 0, stream>>>(ei, packed, cnt, stats, flag);
  wprep_k<<<480, 256, 0, stream>>>(W1, W2, fW1, fW2, wt);
  scatter_k<<<filtBlocks, 256, 0, stream>>>(packed, cnt, csrT);

  for (int l = 0; l < 3; ++l) {
    gather_k<<<gathBlocks, 256, 0, stream>>>(cnt, csrT, x16s, h16s);
    gemm_k<1, 128, 0, 1, 1, 0><<<gemmBlocks, 256, 0, stream>>>(
        h16s, wt + (size_t)l * 16384, b1 + l * 128, nullptr, nullptr, nullptr,
        t16, stats + 256 * l);
    gemm_k<2, 128, 1, 0, 0, 1><<<gemmBlocks, 256, 0, stream>>>(
        t16, wt + (size_t)(3 + l) * 16384, b2 + l * 128, stats + 256 * l,
        g1 + l * 128, be1 + l * 128, x16s, nullptr);
  }

  // final MLP: Linear -> BN -> ReLU -> Linear, out fp32 [NN x 64]
  gemm_k<1, 128, 0, 1, 1, 0><<<gemmBlocks, 256, 0, stream>>>(
      x16s, wt + (size_t)6 * 16384, fb1, nullptr, nullptr, nullptr, t16,
      stats + 768);
  gemm_k<2, 64, 2, 0, 0, 0><<<gemmBlocks, 256, 0, stream>>>(
      t16, wt + (size_t)7 * 16384, fb2, stats + 768, fg1, fbe1, (float*)d_out,
      nullptr);
}

// Round 4
// 595.444 us; speedup vs baseline: 1.2192x; 1.2192x over previous
//
#include <hip/hip_runtime.h>

#define NN 100000
#define NE 1600000
#define DD 128
#define CAP 56      // padded-CSR capacity; P(Poisson(16) >= 56) ~ 5e-15
#define NGROUP 256  // edge-slice groups for filtered scatter

// ---------- bf16 helpers (manual, RNE) ----------
static __device__ __forceinline__ unsigned short f2b(float f) {
  unsigned int x = __float_as_uint(f);
  unsigned int r = x + 0x7fffu + ((x >> 16) & 1u);
  return (unsigned short)(r >> 16);
}
static __device__ __forceinline__ float b2f(unsigned short u) {
  return __uint_as_float(((unsigned int)u) << 16);
}

typedef __attribute__((ext_vector_type(8))) short short8;
typedef __attribute__((ext_vector_type(4))) float f32x4;

union V8 {
  uint4 u4;
  short8 s8;
  unsigned short us[8];
};

// ---------- edge-index dtype detector ----------
__global__ void detect_k(const int* __restrict__ ei, int* __restrict__ flag) {
  int v = ei[2 * threadIdx.x + 1];
  unsigned long long b = __ballot(v != 0);
  if (threadIdx.x == 0) *flag = (b == 0ull) ? 1 : 0;
}

// ---------- fp32 -> bf16 cast (x input, row-major) ----------
__global__ __launch_bounds__(256) void cast_k(const float* __restrict__ x,
                                              unsigned short* __restrict__ x16) {
  size_t i = ((size_t)blockIdx.x * 256 + threadIdx.x) * 8;
  f32x4 a = *(const f32x4*)(x + i);
  f32x4 b = *(const f32x4*)(x + i + 4);
  V8 v;
#pragma unroll
  for (int j = 0; j < 4; ++j) {
    v.us[j] = f2b(a[j]);
    v.us[4 + j] = f2b(b[j]);
  }
  *(uint4*)(x16 + i) = v.u4;
}

// ---------- pack edges to int2 (src,dst) + zero cnt + zero all BN stat buffers ----------
__global__ __launch_bounds__(256) void pack_k(const int* __restrict__ ei,
                                              int2* __restrict__ packed,
                                              int* __restrict__ cnt,
                                              float* __restrict__ stats,
                                              const int* __restrict__ flag) {
  const int mode = *flag;
  const int gid = blockIdx.x * 256 + threadIdx.x;
  int s, d;
  if (mode) {  // int64 little-endian, values < 2^31: low word at even offset
    s = ((const int2*)ei)[gid].x;
    d = ((const int2*)ei)[(size_t)NE + gid].x;
  } else {
    s = ei[gid];
    d = ei[NE + gid];
  }
  packed[gid] = make_int2(s, d);
  if (gid < NN) cnt[gid] = 0;
  if (gid < 1024) stats[gid] = 0.f;  // 4 layers x (sum[128], sumsq[128])
}

// ---------- padded-CSR scatter, XCD-range-filtered (R0 structure, control) ----------
__global__ __launch_bounds__(256) void scatter_k(const int2* __restrict__ packed,
                                                 int* __restrict__ cnt,
                                                 int* __restrict__ csr) {
  const int r = blockIdx.x & 7;
  const int g = blockIdx.x >> 3;
  const int lo = r * (NN / 8), hi = lo + (NN / 8);
  for (int e = g * 256 + threadIdx.x; e < NE; e += NGROUP * 256) {
    int2 sd = packed[e];
    if (sd.y >= lo && sd.y < hi) {
      int c = atomicAdd(&cnt[sd.y], 1);
      if (c < CAP) csr[(size_t)sd.y * CAP + c] = sd.x;
    }
  }
}

// ---------- weight prep: transpose+cast all 7 matrices to bf16 wT[n][k] ----------
__global__ __launch_bounds__(256) void wprep_k(const float* __restrict__ W1,
                                               const float* __restrict__ W2,
                                               const float* __restrict__ fW1,
                                               const float* __restrict__ fW2,
                                               unsigned short* __restrict__ wt) {
  int b = blockIdx.x;
  const float* src;
  int moff, N;
  if (b < 192) {
    int m = b >> 6;
    src = W1 + m * 16384;
    moff = m * 16384;
    N = 128;
    b &= 63;
  } else if (b < 384) {
    int m = (b - 192) >> 6;
    src = W2 + m * 16384;
    moff = (3 + m) * 16384;
    N = 128;
    b = (b - 192) & 63;
  } else if (b < 448) {
    src = fW1;
    moff = 6 * 16384;
    N = 128;
    b -= 384;
  } else {
    src = fW2;
    moff = 7 * 16384;
    N = 64;
    b -= 448;
  }
  int idx = b * 256 + threadIdx.x;  // n*128 + k
  int n = idx >> 7, k = idx & 127;
  if (n < N) wt[moff + idx] = f2b(src[(size_t)k * N + n]);
}

// ---------- gather-reduce (R0 structure): h16[node] = x16[node] + sum_{s in in(node)} x16[s] ----------
// 16 threads/node, 8 cols each; unroll-4 independent accumulators.
// Each neighbor read = 16 lanes x 16B contiguous = full 256B row, 100% line use.
__global__ __launch_bounds__(256) void gather_k(const int* __restrict__ cnt,
                                                const int* __restrict__ csr,
                                                const unsigned short* __restrict__ x16,
                                                unsigned short* __restrict__ h16) {
  const int node = blockIdx.x * 16 + (threadIdx.x >> 4);
  const int l = threadIdx.x & 15;
  const int beg = node * CAP;
  const int end = beg + cnt[node];
  V8 v;
  v.u4 = *(const uint4*)(x16 + (size_t)node * DD + l * 8);
  float a0[8], a1[8], a2[8], a3[8];
#pragma unroll
  for (int j = 0; j < 8; ++j) {
    a0[j] = b2f(v.us[j]);
    a1[j] = 0.f;
    a2[j] = 0.f;
    a3[j] = 0.f;
  }
  int p = beg;
  for (; p + 4 <= end; p += 4) {
    const int s0 = csr[p], s1 = csr[p + 1], s2 = csr[p + 2], s3 = csr[p + 3];
    V8 w0, w1, w2, w3;
    w0.u4 = *(const uint4*)(x16 + (size_t)s0 * DD + l * 8);
    w1.u4 = *(const uint4*)(x16 + (size_t)s1 * DD + l * 8);
    w2.u4 = *(const uint4*)(x16 + (size_t)s2 * DD + l * 8);
    w3.u4 = *(const uint4*)(x16 + (size_t)s3 * DD + l * 8);
#pragma unroll
    for (int j = 0; j < 8; ++j) {
      a0[j] += b2f(w0.us[j]);
      a1[j] += b2f(w1.us[j]);
      a2[j] += b2f(w2.us[j]);
      a3[j] += b2f(w3.us[j]);
    }
  }
  for (; p < end; ++p) {
    const int s0 = csr[p];
    V8 w0;
    w0.u4 = *(const uint4*)(x16 + (size_t)s0 * DD + l * 8);
#pragma unroll
    for (int j = 0; j < 8; ++j) a0[j] += b2f(w0.us[j]);
  }
  V8 o;
#pragma unroll
  for (int j = 0; j < 8; ++j) o.us[j] = f2b((a0[j] + a1[j]) + (a2[j] + a3[j]));
  *(uint4*)(h16 + (size_t)node * DD + l * 8) = o.u4;
}

// ---------- MFMA GEMM: C[M x NCOLS] = A[M x 128] @ wT^T + bias ----------
// 512 threads / 128 rows per block: the 36 KB weight stage serves 2x the rows
// of the old 64-row block (halves prologue cost/row, doubles LDS-limited occ).
// A-row global loads are issued BEFORE the LDS staging so their latency hides
// under the weight prologue instead of serializing after __syncthreads.
// AMODE: 1 = A bf16 plain, 2 = A bf16 with BN(scale,shift from raw stats)+ReLU
// EPI:   0 = store bf16, 1 = relu + store bf16, 2 = store fp32
// STATS: 1 = accumulate per-column sum/sumsq of the (rounded) output
template <int AMODE, int NCOLS, int EPI, int STATS>
__global__ __launch_bounds__(512) void gemm_k(const unsigned short* __restrict__ Aptr,
                                              const unsigned short* __restrict__ wT,
                                              const float* __restrict__ bias,
                                              const float* __restrict__ bn_stats,
                                              const float* __restrict__ gamma,
                                              const float* __restrict__ beta,
                                              void* __restrict__ Cptr,
                                              float* __restrict__ stats_out) {
  __shared__ unsigned short bT[NCOLS][136];  // 136: 16B-aligned rows, bank-spread
  __shared__ float biasS[NCOLS];
  __shared__ float scS[128];
  __shared__ float shS[128];
  __shared__ float sS[NCOLS];
  __shared__ float s2S[NCOLS];
  const int tid = threadIdx.x;
  const int wv = tid >> 6;
  const int lane = tid & 63;
  const int l16 = lane & 15;
  const int quad = lane >> 4;
  const int arow = blockIdx.x * 128 + wv * 16 + l16;  // A row (m = lane&15)
  const bool rv = arow < NN;

  // ---- A loads first: latency overlaps the weight staging below ----
  V8 afr[4];
#pragma unroll
  for (int kc = 0; kc < 4; ++kc) {
    if (rv) {
      afr[kc].u4 = *(const uint4*)(Aptr + (size_t)arow * DD + kc * 32 + quad * 8);
    } else {
      afr[kc].u4 = make_uint4(0u, 0u, 0u, 0u);
    }
  }

  // prologue: straight vectorized copy of pre-transposed weights
  for (int i = tid; i < NCOLS * 16; i += 512) {
    int n = i >> 4, k8 = (i & 15) << 3;
    *(uint4*)&bT[n][k8] = *(const uint4*)(wT + n * 128 + k8);
  }
  if (tid < NCOLS) biasS[tid] = bias[tid];
  if (AMODE == 2 && tid < 128) {
    const float inv_n = 1.0f / (float)NN;
    float mu = bn_stats[tid] * inv_n;
    float var = bn_stats[128 + tid] * inv_n - mu * mu;
    float sc = gamma[tid] * rsqrtf(var + 1e-5f);
    scS[tid] = sc;
    shS[tid] = beta[tid] - mu * sc;
  }
  if (STATS && tid < NCOLS) {
    sS[tid] = 0.f;
    s2S[tid] = 0.f;
  }
  __syncthreads();

  f32x4 acc[NCOLS / 16];
#pragma unroll
  for (int nt = 0; nt < NCOLS / 16; ++nt) acc[nt] = (f32x4)(0.0f);

#pragma unroll
  for (int kc = 0; kc < 4; ++kc) {
    const int k0 = kc * 32 + quad * 8;
    V8 af = afr[kc];
    if (AMODE == 2) {
#pragma unroll
      for (int j = 0; j < 8; ++j) {
        float f = fmaf(b2f(af.us[j]), scS[k0 + j], shS[k0 + j]);
        af.us[j] = f2b(fmaxf(f, 0.0f));
      }
    }
#pragma unroll
    for (int nt = 0; nt < NCOLS / 16; ++nt) {
      V8 bf;
      bf.u4 = *(const uint4*)&bT[nt * 16 + l16][k0];
      acc[nt] = __builtin_amdgcn_mfma_f32_16x16x32_bf16(af.s8, bf.s8, acc[nt], 0, 0, 0);
    }
  }

  // C/D layout: col = lane&15, row = quad*4 + reg
  const int r0 = blockIdx.x * 128 + wv * 16 + quad * 4;
#pragma unroll
  for (int nt = 0; nt < NCOLS / 16; ++nt) {
    const int col = nt * 16 + l16;
    const float bv = biasS[col];
    float s = 0.f, s2 = 0.f;
#pragma unroll
    for (int i = 0; i < 4; ++i) {
      const int r = r0 + i;
      if (r < NN) {
        float v = acc[nt][i] + bv;
        if (EPI == 1) v = fmaxf(v, 0.0f);
        if (EPI == 2) {
          ((float*)Cptr)[(size_t)r * NCOLS + col] = v;
        } else {
          unsigned short us = f2b(v);
          ((unsigned short*)Cptr)[(size_t)r * NCOLS + col] = us;
          if (STATS) {
            float vr = b2f(us);  // stats on rounded value (matches gemm2's input)
            s += vr;
            s2 += vr * vr;
          }
        }
      }
    }
    if (STATS) {
      s += __shfl_xor(s, 16);
      s += __shfl_xor(s, 32);
      s2 += __shfl_xor(s2, 16);
      s2 += __shfl_xor(s2, 32);
      if (quad == 0) {
        atomicAdd(&sS[col], s);
        atomicAdd(&s2S[col], s2);
      }
    }
  }
  if (STATS) {
    __syncthreads();
    if (tid < NCOLS) {
      atomicAdd(&stats_out[tid], sS[tid]);
      atomicAdd(&stats_out[128 + tid], s2S[tid]);
    }
  }
}

// ---------- launch ----------
extern "C" void kernel_launch(void* const* d_in, const int* in_sizes, int n_in,
                              void* d_out, int out_size, void* d_ws, size_t ws_size,
                              hipStream_t stream) {
  const float* x = (const float*)d_in[0];
  const int* ei = (const int*)d_in[1];
  const float* W1 = (const float*)d_in[2];
  const float* b1 = (const float*)d_in[3];
  const float* g1 = (const float*)d_in[4];
  const float* be1 = (const float*)d_in[5];
  const float* W2 = (const float*)d_in[6];
  const float* b2 = (const float*)d_in[7];
  const float* fW1 = (const float*)d_in[8];
  const float* fb1 = (const float*)d_in[9];
  const float* fg1 = (const float*)d_in[10];
  const float* fbe1 = (const float*)d_in[11];
  const float* fW2 = (const float*)d_in[12];
  const float* fb2 = (const float*)d_in[13];

  char* ws = (char*)d_ws;
  unsigned short* x16 = (unsigned short*)ws;                       // 25.6 MB
  unsigned short* h16 = (unsigned short*)(ws + (size_t)25600000);  // 25.6 MB
  unsigned short* t16 = (unsigned short*)(ws + (size_t)51200000);  // 25.6 MB
  int2* packed = (int2*)t16;  // 12.8 MB, consumed by scatter before t16 is written
  int* csr = (int*)(ws + (size_t)76800000);       // NN*CAP*4 = 22.4 MB
  int* cnt = (int*)(ws + (size_t)99200000);       // 400 KB
  float* stats = (float*)(ws + (size_t)99600000); // 4 KB: 4 layers x 256
  int* flag = (int*)(ws + (size_t)99604096);
  unsigned short* wt = (unsigned short*)(ws + (size_t)99605504);   // 262 KB

  const int vecBlocks = (NN * DD) / (256 * 8);  // 6250
  const int gemmBlocks = (NN + 127) / 128;      // 782
  const int edgeBlocks = NE / 256;              // 6250
  const int filtBlocks = NGROUP * 8;            // 2048
  const int nodeBlocks = NN / 16;               // 6250

  detect_k<<<1, 64, 0, stream>>>(ei, flag);
  cast_k<<<vecBlocks, 256, 0, stream>>>(x, x16);
  pack_k<<<edgeBlocks, 256, 0, stream>>>(ei, packed, cnt, stats, flag);
  wprep_k<<<480, 256, 0, stream>>>(W1, W2, fW1, fW2, wt);
  scatter_k<<<filtBlocks, 256, 0, stream>>>(packed, cnt, csr);

  for (int l = 0; l < 3; ++l) {
    gather_k<<<nodeBlocks, 256, 0, stream>>>(cnt, csr, x16, h16);
    gemm_k<1, 128, 0, 1><<<gemmBlocks, 512, 0, stream>>>(
        h16, wt + (size_t)l * 16384, b1 + l * 128, nullptr, nullptr, nullptr,
        t16, stats + 256 * l);
    gemm_k<2, 128, 1, 0><<<gemmBlocks, 512, 0, stream>>>(
        t16, wt + (size_t)(3 + l) * 16384, b2 + l * 128, stats + 256 * l,
        g1 + l * 128, be1 + l * 128, x16, nullptr);
  }

  // final MLP: Linear -> BN -> ReLU -> Linear, out fp32 [NN x 64]
  gemm_k<1, 128, 0, 1><<<gemmBlocks, 512, 0, stream>>>(
      x16, wt + (size_t)6 * 16384, fb1, nullptr, nullptr, nullptr, t16,
      stats + 768);
  gemm_k<2, 64, 2, 0><<<gemmBlocks, 512, 0, stream>>>(
      t16, wt + (size_t)7 * 16384, fb2, stats + 768, fg1, fbe1, (float*)d_out,
      nullptr);
}